// Round 1
// baseline (302.850 us; speedup 1.0000x reference)
//
#include <hip/hip_runtime.h>
#include <math.h>

#define NBATCH 2
#define KBOX   512
#define CCH    256
#define PP     7
#define NBIN   (PP*PP)        // 49
#define NSAMP  (NBIN*4)       // 196 samples (2x2 per bin)
#define COUT   (CCH*NBIN)     // 12544 outputs per box

__global__ __launch_bounds__(256) void roi_align_kernel(
    const float* __restrict__ f2, const float* __restrict__ f3,
    const float* __restrict__ f4, const float* __restrict__ f5,
    const float* __restrict__ boxes, float* __restrict__ out)
{
    const int m   = blockIdx.x;       // box index 0..1023
    const int tid = threadIdx.x;
    const int b   = m / KBOX;         // batch index

    __shared__ int   s_off[NSAMP][4];
    __shared__ float s_w  [NSAMP][4];

    // ---- box, level selection (all threads, redundant & cheap) ----
    const float x1 = boxes[m*4+0];
    const float y1 = boxes[m*4+1];
    const float x2 = boxes[m*4+2];
    const float y2 = boxes[m*4+3];

    const float area = (x2 - x1) * (y2 - y1);
    const float size = sqrtf(area);
    float lvlf = floorf(4.0f + log2f(size / 224.0f + 1e-8f));
    lvlf = fminf(fmaxf(lvlf, 2.0f), 5.0f);
    const int lvl = (int)lvlf - 2;    // 0..3

    const int   H     = 256 >> lvl;   // square feature maps
    const float scale = 0.25f / (float)(1 << lvl);

    const float* fptr = (lvl == 0) ? f2 : (lvl == 1) ? f3 : (lvl == 2) ? f4 : f5;
    const float* fbase = fptr + (size_t)b * CCH * H * H;   // [C][H][H] for this batch

    // aligned=True: subtract 0.5 after scaling
    const float bx1 = x1 * scale - 0.5f;
    const float by1 = y1 * scale - 0.5f;
    const float bx2 = x2 * scale - 0.5f;
    const float by2 = y2 * scale - 0.5f;
    const float bin_w = (bx2 - bx1) / 7.0f;
    const float bin_h = (by2 - by1) / 7.0f;
    const float Hf = (float)H;

    // ---- phase 1: per-sample offsets + weights into LDS ----
    if (tid < NSAMP) {
        const int bin = tid >> 2;       // 0..48
        const int s   = tid & 3;        // sample within bin
        const int py  = bin / 7;
        const int px  = bin % 7;
        const int iy  = s >> 1;
        const int ix  = s & 1;

        // g = (idx + 0.5)/S, idx = p*2 + i
        const float gy = ((float)(2*py + iy) + 0.5f) * 0.5f;
        const float gx = ((float)(2*px + ix) + 0.5f) * 0.5f;
        const float yy = by1 + gy * bin_h;
        const float xx = bx1 + gx * bin_w;

        const bool vy = (yy >= -1.0f) && (yy <= Hf);
        const bool vx = (xx >= -1.0f) && (xx <= Hf);
        const bool valid = vy && vx;

        const float yc = fmaxf(yy, 0.0f);
        const float xc = fmaxf(xx, 0.0f);
        int yl = min((int)floorf(yc), H - 1);
        int xl = min((int)floorf(xc), H - 1);
        const int yh = min(yl + 1, H - 1);
        const int xh = min(xl + 1, H - 1);
        const float fy = yc - (float)yl;
        const float fx = xc - (float)xl;

        const float vmask = valid ? 1.0f : 0.0f;
        const float w00 = (1.0f - fy) * (1.0f - fx) * vmask;
        const float w01 = (1.0f - fy) * fx          * vmask;
        const float w10 = fy          * (1.0f - fx) * vmask;
        const float w11 = fy          * fx          * vmask;

        s_off[tid][0] = yl * H + xl;
        s_off[tid][1] = yl * H + xh;
        s_off[tid][2] = yh * H + xl;
        s_off[tid][3] = yh * H + xh;
        s_w  [tid][0] = w00;
        s_w  [tid][1] = w01;
        s_w  [tid][2] = w10;
        s_w  [tid][3] = w11;
    }
    __syncthreads();

    // ---- phase 2: 12544 outputs per box, coalesced writes ----
    float* outm = out + (size_t)m * COUT;
    const int HH = H * H;

    #pragma unroll 1
    for (int i = tid; i < COUT; i += 256) {
        const int c   = i / NBIN;
        const int bin = i - c * NBIN;
        const float* plane = fbase + (size_t)c * HH;

        float acc = 0.0f;
        #pragma unroll
        for (int s = 0; s < 4; ++s) {
            const int sidx = bin * 4 + s;
            acc += s_w[sidx][0] * plane[s_off[sidx][0]];
            acc += s_w[sidx][1] * plane[s_off[sidx][1]];
            acc += s_w[sidx][2] * plane[s_off[sidx][2]];
            acc += s_w[sidx][3] * plane[s_off[sidx][3]];
        }
        outm[i] = 0.25f * acc;   // mean over 2x2 samples
    }
}

extern "C" void kernel_launch(void* const* d_in, const int* in_sizes, int n_in,
                              void* d_out, int out_size, void* d_ws, size_t ws_size,
                              hipStream_t stream) {
    const float* f2    = (const float*)d_in[0];
    const float* f3    = (const float*)d_in[1];
    const float* f4    = (const float*)d_in[2];
    const float* f5    = (const float*)d_in[3];
    const float* boxes = (const float*)d_in[4];
    float* outp = (float*)d_out;

    dim3 grid(NBATCH * KBOX);   // 1024 blocks, one per box
    dim3 block(256);
    roi_align_kernel<<<grid, block, 0, stream>>>(f2, f3, f4, f5, boxes, outp);
}

// Round 2
// 165.602 us; speedup vs baseline: 1.8288x; 1.8288x over previous
//
#include <hip/hip_runtime.h>
#include <math.h>

#define NBATCH 2
#define KBOX   512
#define CCH    256
#define PP     7
#define NBIN   (PP*PP)        // 49
#define NSAMP  (NBIN*4)       // 196 samples (2x2 per bin)
#define CG     4              // channel groups per box (blocks per box)
#define CPG    (CCH/CG)       // 64 channels per block
#define COUT_SUB (CPG*NBIN)   // 3136 outputs per block
#define COUT   (CCH*NBIN)     // 12544 outputs per box

__global__ __launch_bounds__(256) void roi_align_kernel(
    const float* __restrict__ f2, const float* __restrict__ f3,
    const float* __restrict__ f4, const float* __restrict__ f5,
    const float* __restrict__ boxes, float* __restrict__ out)
{
    const int bid = blockIdx.x;
    const int m   = bid >> 2;         // box index 0..1023
    const int cg  = bid & 3;          // channel group 0..3
    const int tid = threadIdx.x;
    const int b   = m / KBOX;         // batch index

    // transposed tables: [tap 0..15][bin] -> consecutive lanes (consecutive
    // bins) hit consecutive LDS addresses -> conflict-free
    __shared__ int   s_off[16][NBIN];
    __shared__ float s_w  [16][NBIN];

    // ---- box, level selection (all threads, redundant & cheap) ----
    const float x1 = boxes[m*4+0];
    const float y1 = boxes[m*4+1];
    const float x2 = boxes[m*4+2];
    const float y2 = boxes[m*4+3];

    const float area = (x2 - x1) * (y2 - y1);
    const float size = sqrtf(area);
    float lvlf = floorf(4.0f + log2f(size / 224.0f + 1e-8f));
    lvlf = fminf(fmaxf(lvlf, 2.0f), 5.0f);
    const int lvl = (int)lvlf - 2;    // 0..3

    const int   H     = 256 >> lvl;   // square feature maps
    const int   HH    = H * H;
    const float scale = 0.25f / (float)(1 << lvl);

    const float* fptr = (lvl == 0) ? f2 : (lvl == 1) ? f3 : (lvl == 2) ? f4 : f5;
    // base of this block's first channel plane
    const float* fbase = fptr + ((size_t)b * CCH + (size_t)cg * CPG) * HH;

    // aligned=True: subtract 0.5 after scaling
    const float bx1 = x1 * scale - 0.5f;
    const float by1 = y1 * scale - 0.5f;
    const float bx2 = x2 * scale - 0.5f;
    const float by2 = y2 * scale - 0.5f;
    const float bin_w = (bx2 - bx1) / 7.0f;
    const float bin_h = (by2 - by1) / 7.0f;
    const float Hf = (float)H;

    // ---- phase 1: per-sample offsets + weights into LDS (transposed) ----
    if (tid < NSAMP) {
        const int bin = tid >> 2;       // 0..48
        const int s   = tid & 3;        // sample within bin
        const int py  = bin / 7;
        const int px  = bin % 7;
        const int iy  = s >> 1;
        const int ix  = s & 1;

        const float gy = ((float)(2*py + iy) + 0.5f) * 0.5f;
        const float gx = ((float)(2*px + ix) + 0.5f) * 0.5f;
        const float yy = by1 + gy * bin_h;
        const float xx = bx1 + gx * bin_w;

        const bool vy = (yy >= -1.0f) && (yy <= Hf);
        const bool vx = (xx >= -1.0f) && (xx <= Hf);
        const bool valid = vy && vx;

        const float yc = fmaxf(yy, 0.0f);
        const float xc = fmaxf(xx, 0.0f);
        int yl = min((int)floorf(yc), H - 1);
        int xl = min((int)floorf(xc), H - 1);
        const int yh = min(yl + 1, H - 1);
        const int xh = min(xl + 1, H - 1);
        const float fy = yc - (float)yl;
        const float fx = xc - (float)xl;

        const float vmask = valid ? 1.0f : 0.0f;
        const float w00 = (1.0f - fy) * (1.0f - fx) * vmask;
        const float w01 = (1.0f - fy) * fx          * vmask;
        const float w10 = fy          * (1.0f - fx) * vmask;
        const float w11 = fy          * fx          * vmask;

        const int r = s * 4;            // rows r..r+3 of the transposed table
        s_off[r+0][bin] = yl * H + xl;
        s_off[r+1][bin] = yl * H + xh;
        s_off[r+2][bin] = yh * H + xl;
        s_off[r+3][bin] = yh * H + xh;
        s_w  [r+0][bin] = w00;
        s_w  [r+1][bin] = w01;
        s_w  [r+2][bin] = w10;
        s_w  [r+3][bin] = w11;
    }
    __syncthreads();

    // ---- phase 2: 3136 outputs per block, coalesced nontemporal writes ----
    float* outm = out + (size_t)m * COUT + (size_t)cg * COUT_SUB;

    int i = tid;
    // paired iterations: 32 outstanding gathers per thread
    for (; i + 256 < COUT_SUB; i += 512) {
        const int ia = i;
        const int ib = i + 256;
        const int ca = ia / NBIN;
        const int cb = ib / NBIN;
        const int ba = ia - ca * NBIN;
        const int bb = ib - cb * NBIN;
        const float* pa = fbase + (size_t)ca * HH;
        const float* pb = fbase + (size_t)cb * HH;

        float acca = 0.0f, accb = 0.0f;
        #pragma unroll
        for (int t = 0; t < 16; ++t) {
            acca += s_w[t][ba] * pa[s_off[t][ba]];
            accb += s_w[t][bb] * pb[s_off[t][bb]];
        }
        __builtin_nontemporal_store(0.25f * acca, &outm[ia]);
        __builtin_nontemporal_store(0.25f * accb, &outm[ib]);
    }
    // tail
    for (; i < COUT_SUB; i += 256) {
        const int c   = i / NBIN;
        const int bin = i - c * NBIN;
        const float* plane = fbase + (size_t)c * HH;
        float acc = 0.0f;
        #pragma unroll
        for (int t = 0; t < 16; ++t)
            acc += s_w[t][bin] * plane[s_off[t][bin]];
        __builtin_nontemporal_store(0.25f * acc, &outm[i]);
    }
}

extern "C" void kernel_launch(void* const* d_in, const int* in_sizes, int n_in,
                              void* d_out, int out_size, void* d_ws, size_t ws_size,
                              hipStream_t stream) {
    const float* f2    = (const float*)d_in[0];
    const float* f3    = (const float*)d_in[1];
    const float* f4    = (const float*)d_in[2];
    const float* f5    = (const float*)d_in[3];
    const float* boxes = (const float*)d_in[4];
    float* outp = (float*)d_out;

    dim3 grid(NBATCH * KBOX * CG);   // 4096 blocks, 4 per box
    dim3 block(256);
    roi_align_kernel<<<grid, block, 0, stream>>>(f2, f3, f4, f5, boxes, outp);
}